// Round 7
// baseline (208.629 us; speedup 1.0000x reference)
//
#include <hip/hip_runtime.h>
#include <hip/hip_bf16.h>

#define BB 8
#define CC 128
#define NN 512
#define TT 12
#define HH 4
#define C4 32

typedef float f32x4 __attribute__((ext_vector_type(4)));
typedef __bf16 bf16x8 __attribute__((ext_vector_type(8)));

// ---------------- kernel A0: transpose W1,W2 into Wt[c][o] (scalar-load friendly)
__global__ __launch_bounds__(256) void wtrans_k(const float* __restrict__ W1,
                                                const float* __restrict__ W2,
                                                float* __restrict__ Wt) {
    int idx = blockIdx.x * 256 + threadIdx.x;   // 0..32767
    int sel = idx >> 14;                        // 0: W1, 1: W2
    int r   = idx & 16383;
    int o = r >> 7, c = r & 127;
    const float* W = sel ? W2 : W1;
    Wt[sel * 16384 + c * 128 + o] = W[r];
}

// ---------------- kernel A: 1x1 convs (fp32 exact), store bf16 [slice][h][n][c4]
// F[slice][h][n][c4] = sum_c W[(c4*4+h), c] * seq[b, c, n0+n, t],  slice = b*T+t
// Structure: lane <-> n (per-lane ds_read_b32, 2-way aliasing = free), wave-uniform
// o-block of 32 channels whose weights come in via the scalar/uniform path.
__global__ __launch_bounds__(256) void conv_k(const float* __restrict__ seq,
                                              const float* __restrict__ Wt,
                                              __hip_bfloat16* __restrict__ F1,
                                              __hip_bfloat16* __restrict__ F2) {
    __shared__ float S[CC][64];                       // 32 KB, [c][n]

    int bid = blockIdx.x;               // 768 = 8 xcd * (8 b * 12 t)
    int xcd = bid & 7, g = bid >> 3;    // consecutive bids round-robin XCDs
    int t   = g % TT;
    int b   = g / TT;                   // 0..7
    int n0  = xcd * 64;                 // n-tile pinned per XCD: t-siblings share seq lines
    int slice = b * TT + t;

    int tid = threadIdx.x;
    int n   = tid & 63;                                   // lane id == n offset
    int og  = __builtin_amdgcn_readfirstlane(tid >> 6);   // wave-uniform o-block 0..3

    // stage seq[b][c][n0..n0+63][t] -> S[c][n]
    for (int idx = tid; idx < CC * 64; idx += 256) {
        int c = idx >> 6, nn = idx & 63;
        S[c][nn] = seq[((size_t)(b * CC + c) * NN + (n0 + nn)) * TT + t];
    }
    __syncthreads();

    for (int conv = 0; conv < 2; ++conv) {
        const float* Wv = Wt + conv * 16384 + og * 32;    // uniform base -> s_load

        float acc[4][8];                                  // [h][j], o = og*32 + 4*j + h
#pragma unroll
        for (int h = 0; h < 4; ++h)
#pragma unroll
            for (int j = 0; j < 8; ++j) acc[h][j] = 0.0f;

#pragma unroll 2
        for (int c = 0; c < CC; ++c) {
            float wv[32];
#pragma unroll
            for (int i = 0; i < 32; ++i) wv[i] = Wv[c * 128 + i];   // uniform loads
            float s = S[c][n];                                       // per-lane LDS
#pragma unroll
            for (int h = 0; h < 4; ++h)
#pragma unroll
                for (int j = 0; j < 8; ++j)
                    acc[h][j] = fmaf(wv[4 * j + h], s, acc[h][j]);
        }

        // o = og*32 + 4j + h  ->  h = o&3, c4 = og*8 + j  (j contiguous -> 16B store)
        __hip_bfloat16* Fg = conv ? F2 : F1;
#pragma unroll
        for (int h = 0; h < 4; ++h) {
            bf16x8 v;
#pragma unroll
            for (int j = 0; j < 8; ++j) v[j] = (__bf16)acc[h][j];
            *(bf16x8*)&Fg[((size_t)(slice * HH + h) * NN + (n0 + n)) * C4 + og * 8] = v;
        }
    }
}

// ---------------- kernel B: logits via MFMA (K=32 per head) + sigmoid-mean
__global__ __launch_bounds__(256) void att_k(const __hip_bfloat16* __restrict__ F1,
                                             const __hip_bfloat16* __restrict__ F2,
                                             float* __restrict__ out) {
    int bid = blockIdx.x;                 // 6144 = 8 xcd * 64 tiles * 12
    int xcd = bid & 7, g = bid >> 3;      // keep all 64 tiles of a slice on one XCD
    int tile = g & 63, sg = g >> 6;       // sg 0..11
    int slice = sg * 8 + xcd;             // 0..95
    int ti = tile >> 3, tj = tile & 7;
    int n0 = ti * 64, q0 = tj * 64;

    int tid = threadIdx.x;
    int w = tid >> 6, l = tid & 63;
    int wr = w >> 1, wc = w & 1;          // 4 waves in 2x2 of 32x32
    int nw = n0 + wr * 32, qw = q0 + wc * 32;
    int lr = l & 15, lg = l >> 4;

    const __hip_bfloat16* F1s = F1 + (size_t)slice * HH * NN * C4;
    const __hip_bfloat16* F2s = F2 + (size_t)slice * HH * NN * C4;

    f32x4 oacc[2][2];
#pragma unroll
    for (int i = 0; i < 2; ++i)
#pragma unroll
        for (int j = 0; j < 2; ++j) oacc[i][j] = (f32x4){0.f, 0.f, 0.f, 0.f};

#pragma unroll
    for (int h = 0; h < HH; ++h) {
        const __hip_bfloat16* f1h = F1s + h * NN * C4;
        const __hip_bfloat16* f2h = F2s + h * NN * C4;
        // A frag: row = nw+lr (output n), k-slots 8*lg..+7 (contiguous c4, 16B load)
        bf16x8 a0 = *(const bf16x8*)(f1h + (nw + lr) * C4 + 8 * lg);
        bf16x8 a1 = *(const bf16x8*)(f1h + (nw + 16 + lr) * C4 + 8 * lg);
        // B frag: col = qw+lr (output q), same k-slot mapping (A/B mirror symmetry
        // means any consistent slot->k bijection cancels between operands)
        bf16x8 b0 = *(const bf16x8*)(f2h + (qw + lr) * C4 + 8 * lg);
        bf16x8 b1 = *(const bf16x8*)(f2h + (qw + 16 + lr) * C4 + 8 * lg);
        f32x4 z = {0.f, 0.f, 0.f, 0.f};
        f32x4 l00 = __builtin_amdgcn_mfma_f32_16x16x32_bf16(a0, b0, z, 0, 0, 0);
        f32x4 l01 = __builtin_amdgcn_mfma_f32_16x16x32_bf16(a0, b1, z, 0, 0, 0);
        f32x4 l10 = __builtin_amdgcn_mfma_f32_16x16x32_bf16(a1, b0, z, 0, 0, 0);
        f32x4 l11 = __builtin_amdgcn_mfma_f32_16x16x32_bf16(a1, b1, z, 0, 0, 0);
#pragma unroll
        for (int r = 0; r < 4; ++r) {
            oacc[0][0][r] += __builtin_amdgcn_rcpf(1.0f + __expf(-l00[r]));
            oacc[0][1][r] += __builtin_amdgcn_rcpf(1.0f + __expf(-l01[r]));
            oacc[1][0][r] += __builtin_amdgcn_rcpf(1.0f + __expf(-l10[r]));
            oacc[1][1][r] += __builtin_amdgcn_rcpf(1.0f + __expf(-l11[r]));
        }
    }

    // C/D layout (m89-verified): col = lane&15, row = 4*(lane>>4) + reg
    float* outs = out + (size_t)slice * NN * NN;
#pragma unroll
    for (int i = 0; i < 2; ++i) {
#pragma unroll
        for (int j = 0; j < 2; ++j) {
#pragma unroll
            for (int r = 0; r < 4; ++r) {
                int nn = nw + i * 16 + 4 * lg + r;
                int q  = qw + j * 16 + lr;
                outs[nn * NN + q] = 0.25f * oacc[i][j][r];
            }
        }
    }
}

extern "C" void kernel_launch(void* const* d_in, const int* in_sizes, int n_in,
                              void* d_out, int out_size, void* d_ws, size_t ws_size,
                              hipStream_t stream) {
    const float* seq = (const float*)d_in[0];
    const float* W1  = (const float*)d_in[1];
    const float* W2  = (const float*)d_in[2];
    float* out = (float*)d_out;

    // ws layout: [Wt: 2*16384 f32 = 128KB][F1: 12.58MB bf16][F2: 12.58MB bf16]
    float* Wt = (float*)d_ws;
    __hip_bfloat16* F1 = (__hip_bfloat16*)((char*)d_ws + 2 * 16384 * sizeof(float));
    __hip_bfloat16* F2 = F1 + (size_t)96 * HH * NN * C4;

    wtrans_k<<<128, 256, 0, stream>>>(W1, W2, Wt);
    conv_k<<<768, 256, 0, stream>>>(seq, Wt, F1, F2);
    att_k<<<6144, 256, 0, stream>>>(F1, F2, out);
}